// Round 4
// baseline (225.737 us; speedup 1.0000x reference)
//
#include <hip/hip_runtime.h>
#include <hip/hip_bf16.h>

// MultiHeadAttention: B=4, S=2048, D=512, H=16, dh=32 (gfx950)
// Pipeline: wcvt(Wo->bf16) -> proj(Q,K,V per-head, hi/lo split) -> flash attn -> out proj.
// R4: attn occupancy 4->8 waves/SIMD: 16 q-rows/wave (1 qi), grid 2048,
//     __launch_bounds__(256,8). Swapped QK + stride-68 P tile kept (0 conflicts).

typedef __attribute__((ext_vector_type(8))) short bf16x8;   // 8 bf16 in 4 VGPRs
typedef __attribute__((ext_vector_type(4))) float f32x4;

#define MFMA16(a, b, c) __builtin_amdgcn_mfma_f32_16x16x32_bf16(a, b, c, 0, 0, 0)

static __device__ __forceinline__ unsigned short f2bf(float f) {
  __bf16 h = (__bf16)f;                      // RNE cvt
  union { __bf16 h; unsigned short u; } c; c.h = h; return c.u;
}
static __device__ __forceinline__ float bf2f(unsigned short u) {
  union { unsigned u; float f; } c; c.u = ((unsigned)u) << 16; return c.f;
}

// load 8 consecutive floats, split each into bf16 hi + bf16 residual(lo)
static __device__ __forceinline__ void load8_split(const float* p, bf16x8& hi, bf16x8& lo) {
  float4 a = *(const float4*)p;
  float4 b = *(const float4*)(p + 4);
  float v[8] = {a.x, a.y, a.z, a.w, b.x, b.y, b.z, b.w};
  #pragma unroll
  for (int j = 0; j < 8; ++j) {
    unsigned short h = f2bf(v[j]);
    hi[j] = (short)h;
    lo[j] = (short)f2bf(v[j] - bf2f(h));
  }
}

// ---------------- kernel 1: Wo (512x512 f32) -> bf16 ----------------
__global__ __launch_bounds__(256) void wcvt_kernel(const float* __restrict__ Wo,
                                                   ushort* __restrict__ Wob) {
  int i = (blockIdx.x * 256 + threadIdx.x) * 4;   // grid 256 -> covers 512*512
  float4 v = *(const float4*)&Wo[i];
  ushort4 o;
  o.x = f2bf(v.x); o.y = f2bf(v.y); o.z = f2bf(v.z); o.w = f2bf(v.w);
  *(ushort4*)&Wob[i] = o;
}

// ---------------- kernel 2: per-head projections ----------------
// Qp[bh][s][e] (scaled by log2e/sqrt(32)), Kp[bh][s][e], Vt[bh][e][s]  (bf16)
__global__ __launch_bounds__(256) void proj_kernel(
    const float* __restrict__ key, const float* __restrict__ query,
    const float* __restrict__ value,
    const float* __restrict__ Wq, const float* __restrict__ Wk,
    const float* __restrict__ Wv,
    ushort* __restrict__ Qp, ushort* __restrict__ Kp, ushort* __restrict__ Vt) {
  const int tid = threadIdx.x;
  const int l = tid & 63, wid = tid >> 6;
  const int lr = l & 15, lc = l >> 4;
  const int task = blockIdx.x * 4 + wid;     // 8192 tasks: (b, s-tile16, h)
  const int h = task & 15;
  const int st = (task >> 4) & 127;
  const int b = task >> 11;
  const int bh = b * 16 + h;
  const size_t xoff = ((size_t)b * 2048 + st * 16 + lr) * 512 + h * 32 + lc * 8;
  const float ALPHA = 0.2550354039f;         // log2(e)/sqrt(32)

  #pragma unroll
  for (int t = 0; t < 3; ++t) {
    const float* x = (t == 0) ? query : (t == 1) ? key : value;
    const float* W = (t == 0) ? Wq : (t == 1) ? Wk : Wv;
    bf16x8 xh, xl;
    load8_split(x + xoff, xh, xl);
    #pragma unroll
    for (int eh = 0; eh < 2; ++eh) {
      bf16x8 wh, wl;
      load8_split(W + (size_t)(eh * 16 + lr) * 32 + lc * 8, wh, wl);
      f32x4 acc = {0.f, 0.f, 0.f, 0.f};
      acc = MFMA16(xh, wh, acc);   // hi*hi + hi*lo + lo*hi: ~fp32-accurate projection
      acc = MFMA16(xh, wl, acc);
      acc = MFMA16(xl, wh, acc);
      if (t == 0) {
        #pragma unroll
        for (int r = 0; r < 4; ++r)
          Qp[((size_t)bh * 2048 + st * 16 + lc * 4 + r) * 32 + eh * 16 + lr] =
              f2bf(acc[r] * ALPHA);
      } else if (t == 1) {
        #pragma unroll
        for (int r = 0; r < 4; ++r)
          Kp[((size_t)bh * 2048 + st * 16 + lc * 4 + r) * 32 + eh * 16 + lr] = f2bf(acc[r]);
      } else {                      // V stored transposed: Vt[bh][e][s]
        ushort4 pk;
        pk.x = f2bf(acc[0]); pk.y = f2bf(acc[1]);
        pk.z = f2bf(acc[2]); pk.w = f2bf(acc[3]);
        *(ushort4*)&Vt[((size_t)bh * 32 + eh * 16 + lr) * 2048 + st * 16 + lc * 4] = pk;
      }
    }
  }
}

// ---------------- kernel 3: attention ----------------
// grid 2048: bid>>5 = bh, bid&31 = q-block of 64 rows; 4 waves * 16 q-rows each.
// 8192 waves -> 8 waves/SIMD for latency hiding.
// Swapped QK: sc = mfma(K, Q) -> D[m=k][n=q]; lane (lr,lc) holds k=lc*4+r for q=lr.
// No max-subtraction: logits pre-scaled to log2 units, bounded (|s|<~3).
__global__ __launch_bounds__(256, 8) void attn_kernel(
    const ushort* __restrict__ Qp, const ushort* __restrict__ Kp,
    const ushort* __restrict__ Vt, ushort* __restrict__ Cb) {
  // Per-wave P tile [q=16][k=64], stride 68 ushorts (34 dwords/row: bank shift
  // of 2/row -> b64 writes 1 touch/bank, b64-pair reads at 2-touch minimum;
  // measured 0 conflicts in R1/R3).
  __shared__ ushort plds[4][16][68];
  const int tid = threadIdx.x;
  const int l = tid & 63, w = tid >> 6;
  const int lr = l & 15, lc = l >> 4;
  const int bh = blockIdx.x >> 5;
  const int qblk = blockIdx.x & 31;
  const int b = bh >> 4, h = bh & 15;
  const int q0 = qblk * 64 + w * 16;

  const ushort* Qb = Qp + (size_t)bh * 2048 * 32;
  const ushort* Kb = Kp + (size_t)bh * 2048 * 32;
  const ushort* Vb = Vt + (size_t)bh * 32 * 2048;

  const bf16x8 qf = *(const bf16x8*)&Qb[(size_t)(q0 + lr) * 32 + lc * 8];

  f32x4 octx[2] = {};
  float lsum = 0.f;                    // lane-local partial denom for q = q0+lr
  const f32x4 zero = {0.f, 0.f, 0.f, 0.f};

  for (int kt = 0; kt < 32; ++kt) {
    const int k0 = kt * 64;
    bf16x8 kf[4];
    #pragma unroll
    for (int kg = 0; kg < 4; ++kg)
      kf[kg] = *(const bf16x8*)&Kb[(size_t)(k0 + kg * 16 + lr) * 32 + lc * 8];
    bf16x8 vf[2][2];
    #pragma unroll
    for (int kc = 0; kc < 2; ++kc)
      #pragma unroll
      for (int eh = 0; eh < 2; ++eh)
        vf[kc][eh] = *(const bf16x8*)&Vb[(size_t)(eh * 16 + lr) * 2048 + k0 + kc * 32 + lc * 8];

    // QK^T, exp2, lane-local denom, pack, staged b64 write -- per kg so the
    // sc fragment stays short-lived (register pressure; 8 waves/SIMD target).
    #pragma unroll
    for (int kg = 0; kg < 4; ++kg) {
      f32x4 sc = MFMA16(kf[kg], qf, zero);   // D[m=k][n=q]
      float p0 = __builtin_amdgcn_exp2f(sc[0]);
      float p1 = __builtin_amdgcn_exp2f(sc[1]);
      float p2 = __builtin_amdgcn_exp2f(sc[2]);
      float p3 = __builtin_amdgcn_exp2f(sc[3]);
      lsum += (p0 + p1) + (p2 + p3);
      ushort4 pk;
      pk.x = f2bf(p0); pk.y = f2bf(p1); pk.z = f2bf(p2); pk.w = f2bf(p3);
      // row q=lr, cols k = kg*16 + lc*4 .. +3 (one 8B write, 8B-aligned)
      *(ushort4*)&plds[w][lr][kg * 16 + lc * 4] = pk;
    }

    // PV: read P A-fragments (two 8B reads each), accumulate ctx.
    // Compiler inserts counted lgkmcnt for the wave-internal RAW.
    #pragma unroll
    for (int kc = 0; kc < 2; ++kc) {
      union { ushort4 q[2]; bf16x8 v; } u;
      u.q[0] = *(const ushort4*)&plds[w][lr][kc * 32 + lc * 8];
      u.q[1] = *(const ushort4*)&plds[w][lr][kc * 32 + lc * 8 + 4];
      #pragma unroll
      for (int eh = 0; eh < 2; ++eh)
        octx[eh] = MFMA16(u.v, vf[kc][eh], octx[eh]);
    }
  }

  // denominator: reduce lsum across the 4 lanes sharing q=lr, broadcast to
  // the octx row owners (row q-local = lc*4+r lives at source lane lc*4+r).
  float s = lsum;
  s += __shfl_xor(s, 16);
  s += __shfl_xor(s, 32);
  float inv[4];
  #pragma unroll
  for (int r = 0; r < 4; ++r)
    inv[r] = 1.0f / __shfl(s, lc * 4 + r);
  #pragma unroll
  for (int eh = 0; eh < 2; ++eh)
    #pragma unroll
    for (int r = 0; r < 4; ++r) {
      float v = octx[eh][r] * inv[r];
      Cb[((size_t)b * 2048 + q0 + lc * 4 + r) * 512 + h * 32 + eh * 16 + lr] = f2bf(v);
    }
}

// ---------------- kernel 4: out = ctx @ Wo^T + bo ----------------
// grid 256: bid>>1 = 64-row q-tile, bid&1 = 256-col n-half; each wave 64x64.
__global__ __launch_bounds__(256) void oproj_kernel(
    const ushort* __restrict__ Cb, const ushort* __restrict__ Wob,
    const float* __restrict__ bo, float* __restrict__ out) {
  const int tid = threadIdx.x;
  const int l = tid & 63, w = tid >> 6;
  const int lr = l & 15, lc = l >> 4;
  const int qt = blockIdx.x >> 1;
  const int nt = blockIdx.x & 1;
  const int r0 = qt * 64;
  const int n0 = nt * 256 + w * 64;

  f32x4 acc[4][4] = {};
  for (int kk = 0; kk < 16; ++kk) {
    const int k0 = kk * 32;
    bf16x8 af[4], bf[4];
    #pragma unroll
    for (int i = 0; i < 4; ++i)
      af[i] = *(const bf16x8*)&Cb[(size_t)(r0 + i * 16 + lr) * 512 + k0 + lc * 8];
    #pragma unroll
    for (int j = 0; j < 4; ++j)
      bf[j] = *(const bf16x8*)&Wob[(size_t)(n0 + j * 16 + lr) * 512 + k0 + lc * 8];
    #pragma unroll
    for (int i = 0; i < 4; ++i)
      #pragma unroll
      for (int j = 0; j < 4; ++j)
        acc[i][j] = MFMA16(af[i], bf[j], acc[i][j]);
  }
  #pragma unroll
  for (int j = 0; j < 4; ++j) {
    float bias = bo[n0 + j * 16 + lr];
    #pragma unroll
    for (int i = 0; i < 4; ++i)
      #pragma unroll
      for (int r = 0; r < 4; ++r)
        out[(size_t)(r0 + i * 16 + lc * 4 + r) * 512 + n0 + j * 16 + lr] =
            acc[i][j][r] + bias;
  }
}

extern "C" void kernel_launch(void* const* d_in, const int* in_sizes, int n_in,
                              void* d_out, int out_size, void* d_ws, size_t ws_size,
                              hipStream_t stream) {
  (void)in_sizes; (void)n_in; (void)out_size; (void)ws_size;
  const float* key   = (const float*)d_in[0];
  const float* query = (const float*)d_in[1];
  const float* value = (const float*)d_in[2];
  const float* Wq    = (const float*)d_in[3];
  const float* Wk    = (const float*)d_in[4];
  const float* Wv    = (const float*)d_in[5];
  const float* Wo    = (const float*)d_in[6];
  const float* bo    = (const float*)d_in[7];
  float* out = (float*)d_out;

  // workspace layout (bf16/ushort elements): Qp, Kp, Vt, Cb (4*16*2048*32 each), Wob (512*512)
  const size_t NT = (size_t)4 * 16 * 2048 * 32;   // 4,194,304
  ushort* ws  = (ushort*)d_ws;
  ushort* Qp  = ws;
  ushort* Kp  = Qp + NT;
  ushort* Vt  = Kp + NT;
  ushort* Cb  = Vt + NT;
  ushort* Wob = Cb + NT;                           // total ~34.1 MB

  hipLaunchKernelGGL(wcvt_kernel, dim3(256), dim3(256), 0, stream, Wo, Wob);
  hipLaunchKernelGGL(proj_kernel, dim3(2048), dim3(256), 0, stream,
                     key, query, value, Wq, Wk, Wv, Qp, Kp, Vt);
  hipLaunchKernelGGL(attn_kernel, dim3(2048), dim3(256), 0, stream, Qp, Kp, Vt, Cb);
  hipLaunchKernelGGL(oproj_kernel, dim3(256), dim3(256), 0, stream, Cb, Wob, bo, out);
}

// Round 5
// 162.694 us; speedup vs baseline: 1.3875x; 1.3875x over previous
//
#include <hip/hip_runtime.h>
#include <hip/hip_bf16.h>

// MultiHeadAttention: B=4, S=2048, D=512, H=16, dh=32 (gfx950)
// Pipeline: wcvt(Wo->bf16) -> proj(QKV per-head, hi/lo split) -> flash attn -> out proj.
// R5: split-K=2 attention. R3 wave shape kept (32 q-rows/wave, VGPR=64, stride-68
//     P tile, 0 bank conflicts); grid 1024->2048 via k-halving (8 blocks/CU) to
//     attack the 46% no-issue latency gap. Partials (f32 octx + lsum) combined by
//     a small second kernel. R4 lesson: never force occupancy via launch_bounds
//     min-waves -- VGPR=32 destroyed MLP.

typedef __attribute__((ext_vector_type(8))) short bf16x8;   // 8 bf16 in 4 VGPRs
typedef __attribute__((ext_vector_type(4))) float f32x4;

#define MFMA16(a, b, c) __builtin_amdgcn_mfma_f32_16x16x32_bf16(a, b, c, 0, 0, 0)

static __device__ __forceinline__ unsigned short f2bf(float f) {
  __bf16 h = (__bf16)f;                      // RNE cvt
  union { __bf16 h; unsigned short u; } c; c.h = h; return c.u;
}
static __device__ __forceinline__ float bf2f(unsigned short u) {
  union { unsigned u; float f; } c; c.u = ((unsigned)u) << 16; return c.f;
}

// load 8 consecutive floats, split each into bf16 hi + bf16 residual(lo)
static __device__ __forceinline__ void load8_split(const float* p, bf16x8& hi, bf16x8& lo) {
  float4 a = *(const float4*)p;
  float4 b = *(const float4*)(p + 4);
  float v[8] = {a.x, a.y, a.z, a.w, b.x, b.y, b.z, b.w};
  #pragma unroll
  for (int j = 0; j < 8; ++j) {
    unsigned short h = f2bf(v[j]);
    hi[j] = (short)h;
    lo[j] = (short)f2bf(v[j] - bf2f(h));
  }
}

// ---------------- kernel 1: Wo (512x512 f32) -> bf16 ----------------
__global__ __launch_bounds__(256) void wcvt_kernel(const float* __restrict__ Wo,
                                                   ushort* __restrict__ Wob) {
  int i = (blockIdx.x * 256 + threadIdx.x) * 4;   // grid 256 -> covers 512*512
  float4 v = *(const float4*)&Wo[i];
  ushort4 o;
  o.x = f2bf(v.x); o.y = f2bf(v.y); o.z = f2bf(v.z); o.w = f2bf(v.w);
  *(ushort4*)&Wob[i] = o;
}

// ---------------- kernel 2: per-head projections ----------------
// Qp[bh][s][e] (scaled by log2e/sqrt(32)), Kp[bh][s][e], Vt[bh][e][s]  (bf16)
__global__ __launch_bounds__(256) void proj_kernel(
    const float* __restrict__ key, const float* __restrict__ query,
    const float* __restrict__ value,
    const float* __restrict__ Wq, const float* __restrict__ Wk,
    const float* __restrict__ Wv,
    ushort* __restrict__ Qp, ushort* __restrict__ Kp, ushort* __restrict__ Vt) {
  const int tid = threadIdx.x;
  const int l = tid & 63, wid = tid >> 6;
  const int lr = l & 15, lc = l >> 4;
  const int task = blockIdx.x * 4 + wid;     // 8192 tasks: (b, s-tile16, h)
  const int h = task & 15;
  const int st = (task >> 4) & 127;
  const int b = task >> 11;
  const int bh = b * 16 + h;
  const size_t xoff = ((size_t)b * 2048 + st * 16 + lr) * 512 + h * 32 + lc * 8;
  const float ALPHA = 0.2550354039f;         // log2(e)/sqrt(32)

  #pragma unroll
  for (int t = 0; t < 3; ++t) {
    const float* x = (t == 0) ? query : (t == 1) ? key : value;
    const float* W = (t == 0) ? Wq : (t == 1) ? Wk : Wv;
    bf16x8 xh, xl;
    load8_split(x + xoff, xh, xl);
    #pragma unroll
    for (int eh = 0; eh < 2; ++eh) {
      bf16x8 wh, wl;
      load8_split(W + (size_t)(eh * 16 + lr) * 32 + lc * 8, wh, wl);
      f32x4 acc = {0.f, 0.f, 0.f, 0.f};
      acc = MFMA16(xh, wh, acc);   // hi*hi + hi*lo + lo*hi: ~fp32-accurate projection
      acc = MFMA16(xh, wl, acc);
      acc = MFMA16(xl, wh, acc);
      if (t == 0) {
        #pragma unroll
        for (int r = 0; r < 4; ++r)
          Qp[((size_t)bh * 2048 + st * 16 + lc * 4 + r) * 32 + eh * 16 + lr] =
              f2bf(acc[r] * ALPHA);
      } else if (t == 1) {
        #pragma unroll
        for (int r = 0; r < 4; ++r)
          Kp[((size_t)bh * 2048 + st * 16 + lc * 4 + r) * 32 + eh * 16 + lr] = f2bf(acc[r]);
      } else {                      // V stored transposed: Vt[bh][e][s]
        ushort4 pk;
        pk.x = f2bf(acc[0]); pk.y = f2bf(acc[1]);
        pk.z = f2bf(acc[2]); pk.w = f2bf(acc[3]);
        *(ushort4*)&Vt[((size_t)bh * 32 + eh * 16 + lr) * 2048 + st * 16 + lc * 4] = pk;
      }
    }
  }
}

// ---------------- kernel 3: attention (optionally split-K) ----------------
// SPLIT=1: grid 2048, blockIdx>>10 = k-half (1024 keys each), partials to Op/Ls.
// SPLIT=0: grid 1024, full 2048 keys, normalized bf16 Cb directly (R3 path).
// 4 waves * 32 q-rows. Swapped QK: sc = mfma(K,Q) -> D[m=k][n=q]; lane (lr,lc)
// holds k=lc*4+r for q=lr. No max-subtraction (logits in log2 units, |s|<~3).
template <int SPLIT>
__global__ __launch_bounds__(256) void attn_kernel(
    const ushort* __restrict__ Qp, const ushort* __restrict__ Kp,
    const ushort* __restrict__ Vt, ushort* __restrict__ Cb,
    float* __restrict__ Op, float* __restrict__ Ls) {
  // Per-wave, per-qi P tile [q=16][k=64], stride 68 ushorts (34 dwords/row ->
  // bank shift 2/row; b64 writes 1 touch/bank, b64-pair reads 2-touch minimum;
  // measured 0 conflicts R1/R3).
  __shared__ ushort plds[2][4][16][68];
  const int tid = threadIdx.x;
  const int l = tid & 63, w = tid >> 6;
  const int lr = l & 15, lc = l >> 4;
  const int qpart = SPLIT ? (blockIdx.x & 1023) : blockIdx.x;
  const int kh = SPLIT ? (int)(blockIdx.x >> 10) : 0;
  const int bh = qpart >> 4;
  const int qblk = qpart & 15;
  const int b = bh >> 4, h = bh & 15;
  const int q0 = qblk * 128 + w * 32;

  const ushort* Qb = Qp + (size_t)bh * 2048 * 32;
  const ushort* Kb = Kp + (size_t)bh * 2048 * 32;
  const ushort* Vb = Vt + (size_t)bh * 32 * 2048;

  bf16x8 qf[2];
  qf[0] = *(const bf16x8*)&Qb[(size_t)(q0 + lr) * 32 + lc * 8];
  qf[1] = *(const bf16x8*)&Qb[(size_t)(q0 + 16 + lr) * 32 + lc * 8];

  f32x4 octx[2][2] = {};
  float lsum[2] = {0.f, 0.f};          // lane-local partial denom for q = q0+qi*16+lr
  const f32x4 zero = {0.f, 0.f, 0.f, 0.f};

  const int t0 = SPLIT ? kh * 16 : 0;
  const int t1 = SPLIT ? kh * 16 + 16 : 32;
  for (int kt = t0; kt < t1; ++kt) {
    const int k0 = kt * 64;
    bf16x8 kf[4];
    #pragma unroll
    for (int kg = 0; kg < 4; ++kg)
      kf[kg] = *(const bf16x8*)&Kb[(size_t)(k0 + kg * 16 + lr) * 32 + lc * 8];
    bf16x8 vf[2][2];
    #pragma unroll
    for (int kc = 0; kc < 2; ++kc)
      #pragma unroll
      for (int eh = 0; eh < 2; ++eh)
        vf[kc][eh] = *(const bf16x8*)&Vb[(size_t)(eh * 16 + lr) * 2048 + k0 + kc * 32 + lc * 8];

    // --- both QK^T fragments first (back-to-back MFMA issue) ---
    f32x4 sc[2][4];
    #pragma unroll
    for (int qi = 0; qi < 2; ++qi)
      #pragma unroll
      for (int kg = 0; kg < 4; ++kg)
        sc[qi][kg] = MFMA16(kf[kg], qf[qi], zero);   // D[m=k][n=q]

    // --- softmax numerators: exp2, lane-local sum, pack, staged b64 write ---
    #pragma unroll
    for (int qi = 0; qi < 2; ++qi)
      #pragma unroll
      for (int kg = 0; kg < 4; ++kg) {
        float p0 = __builtin_amdgcn_exp2f(sc[qi][kg][0]);
        float p1 = __builtin_amdgcn_exp2f(sc[qi][kg][1]);
        float p2 = __builtin_amdgcn_exp2f(sc[qi][kg][2]);
        float p3 = __builtin_amdgcn_exp2f(sc[qi][kg][3]);
        lsum[qi] += (p0 + p1) + (p2 + p3);
        ushort4 pk;
        pk.x = f2bf(p0); pk.y = f2bf(p1); pk.z = f2bf(p2); pk.w = f2bf(p3);
        // row q=lr, cols k = kg*16 + lc*4 .. +3 (one 8B write, 8B-aligned)
        *(ushort4*)&plds[qi][w][lr][kg * 16 + lc * 4] = pk;
      }

    // --- PV: read P A-fragments (two 8B reads), accumulate ctx ---
    // qi1's softmax provides write->read distance for qi0; compiler emits
    // counted lgkmcnt.
    #pragma unroll
    for (int qi = 0; qi < 2; ++qi)
      #pragma unroll
      for (int kc = 0; kc < 2; ++kc) {
        union { ushort4 q[2]; bf16x8 v; } u;
        u.q[0] = *(const ushort4*)&plds[qi][w][lr][kc * 32 + lc * 8];
        u.q[1] = *(const ushort4*)&plds[qi][w][lr][kc * 32 + lc * 8 + 4];
        #pragma unroll
        for (int eh = 0; eh < 2; ++eh)
          octx[qi][eh] = MFMA16(u.v, vf[kc][eh], octx[qi][eh]);
      }
  }

  // lsum reduce across the 4 lanes sharing q=lr (replicated to all 4 after).
  #pragma unroll
  for (int qi = 0; qi < 2; ++qi) {
    float s = lsum[qi];
    s += __shfl_xor(s, 16);
    s += __shfl_xor(s, 32);
    if (SPLIT) {
      // store raw partials: octx f32 + denom (one lane per q-row writes denom)
      const size_t rowb = (size_t)bh * 2048 + q0 + qi * 16;
      if (lc == 0) Ls[(size_t)kh * 64 * 2048 + rowb + lr] = s;
      #pragma unroll
      for (int eh = 0; eh < 2; ++eh)
        #pragma unroll
        for (int r = 0; r < 4; ++r)
          Op[((size_t)kh * 64 * 2048 + rowb + lc * 4 + r) * 32 + eh * 16 + lr] =
              octx[qi][eh][r];
    } else {
      float inv[4];
      #pragma unroll
      for (int r = 0; r < 4; ++r)
        inv[r] = 1.0f / __shfl(s, lc * 4 + r);
      #pragma unroll
      for (int eh = 0; eh < 2; ++eh)
        #pragma unroll
        for (int r = 0; r < 4; ++r) {
          float v = octx[qi][eh][r] * inv[r];
          Cb[((size_t)b * 2048 + q0 + qi * 16 + lc * 4 + r) * 512 + h * 32 + eh * 16 + lr] =
              f2bf(v);
        }
    }
  }
}

// ---------------- kernel 3b: combine split-K partials -> Cb bf16 ----------------
// grid 2048x256: thread t -> row = t>>2 (bh*2048+q), e0 = (t&3)*8.
__global__ __launch_bounds__(256) void combine_kernel(
    const float* __restrict__ Op, const float* __restrict__ Ls,
    ushort* __restrict__ Cb) {
  const int t = blockIdx.x * 256 + threadIdx.x;
  const int row = t >> 2;           // bh*2048 + q
  const int e0 = (t & 3) * 8;
  const int bh = row >> 11, q = row & 2047;
  const int b = bh >> 4, h = bh & 15;
  const size_t HALF = (size_t)64 * 2048;

  float inv = 1.0f / (Ls[row] + Ls[HALF + row]);
  const float4* p0 = (const float4*)&Op[(size_t)row * 32 + e0];
  const float4* p1 = (const float4*)&Op[(HALF + row) * 32 + e0];
  float4 a0 = p0[0], b0 = p0[1];
  float4 a1 = p1[0], b1 = p1[1];
  ushort4 o[2];
  o[0].x = f2bf((a0.x + a1.x) * inv); o[0].y = f2bf((a0.y + a1.y) * inv);
  o[0].z = f2bf((a0.z + a1.z) * inv); o[0].w = f2bf((a0.w + a1.w) * inv);
  o[1].x = f2bf((b0.x + b1.x) * inv); o[1].y = f2bf((b0.y + b1.y) * inv);
  o[1].z = f2bf((b0.z + b1.z) * inv); o[1].w = f2bf((b0.w + b1.w) * inv);
  ushort* dst = &Cb[((size_t)b * 2048 + q) * 512 + h * 32 + e0];
  *(ushort4*)dst = o[0];
  *(ushort4*)(dst + 4) = o[1];
}

// ---------------- kernel 4: out = ctx @ Wo^T + bo ----------------
// grid 256: bid>>1 = 64-row q-tile, bid&1 = 256-col n-half; each wave 64x64.
__global__ __launch_bounds__(256) void oproj_kernel(
    const ushort* __restrict__ Cb, const ushort* __restrict__ Wob,
    const float* __restrict__ bo, float* __restrict__ out) {
  const int tid = threadIdx.x;
  const int l = tid & 63, w = tid >> 6;
  const int lr = l & 15, lc = l >> 4;
  const int qt = blockIdx.x >> 1;
  const int nt = blockIdx.x & 1;
  const int r0 = qt * 64;
  const int n0 = nt * 256 + w * 64;

  f32x4 acc[4][4] = {};
  for (int kk = 0; kk < 16; ++kk) {
    const int k0 = kk * 32;
    bf16x8 af[4], bf[4];
    #pragma unroll
    for (int i = 0; i < 4; ++i)
      af[i] = *(const bf16x8*)&Cb[(size_t)(r0 + i * 16 + lr) * 512 + k0 + lc * 8];
    #pragma unroll
    for (int j = 0; j < 4; ++j)
      bf[j] = *(const bf16x8*)&Wob[(size_t)(n0 + j * 16 + lr) * 512 + k0 + lc * 8];
    #pragma unroll
    for (int i = 0; i < 4; ++i)
      #pragma unroll
      for (int j = 0; j < 4; ++j)
        acc[i][j] = MFMA16(af[i], bf[j], acc[i][j]);
  }
  #pragma unroll
  for (int j = 0; j < 4; ++j) {
    float bias = bo[n0 + j * 16 + lr];
    #pragma unroll
    for (int i = 0; i < 4; ++i)
      #pragma unroll
      for (int r = 0; r < 4; ++r)
        out[(size_t)(r0 + i * 16 + lc * 4 + r) * 512 + n0 + j * 16 + lr] =
            acc[i][j][r] + bias;
  }
}

extern "C" void kernel_launch(void* const* d_in, const int* in_sizes, int n_in,
                              void* d_out, int out_size, void* d_ws, size_t ws_size,
                              hipStream_t stream) {
  (void)in_sizes; (void)n_in; (void)out_size;
  const float* key   = (const float*)d_in[0];
  const float* query = (const float*)d_in[1];
  const float* value = (const float*)d_in[2];
  const float* Wq    = (const float*)d_in[3];
  const float* Wk    = (const float*)d_in[4];
  const float* Wv    = (const float*)d_in[5];
  const float* Wo    = (const float*)d_in[6];
  const float* bo    = (const float*)d_in[7];
  float* out = (float*)d_out;

  // workspace layout (ushorts): Qp, Kp, Vt, Cb (4.19M each), Wob (262144);
  // then f32 split-K partials: Op (2*64*2048*32), Ls (2*64*2048).
  const size_t NT = (size_t)4 * 16 * 2048 * 32;   // 4,194,304
  ushort* ws  = (ushort*)d_ws;
  ushort* Qp  = ws;
  ushort* Kp  = Qp + NT;
  ushort* Vt  = Kp + NT;
  ushort* Cb  = Vt + NT;
  ushort* Wob = Cb + NT;
  float*  Op  = (float*)(Wob + 262144);            // 33.55 MB
  float*  Ls  = Op + (size_t)2 * 64 * 2048 * 32;   // 1.05 MB
  const size_t need = (size_t)(4 * NT + 262144) * 2 +
                      ((size_t)2 * 64 * 2048 * 32 + (size_t)2 * 64 * 2048) * 4;
  const bool split = ws_size >= need;

  hipLaunchKernelGGL(wcvt_kernel, dim3(256), dim3(256), 0, stream, Wo, Wob);
  hipLaunchKernelGGL(proj_kernel, dim3(2048), dim3(256), 0, stream,
                     key, query, value, Wq, Wk, Wv, Qp, Kp, Vt);
  if (split) {
    hipLaunchKernelGGL(attn_kernel<1>, dim3(2048), dim3(256), 0, stream,
                       Qp, Kp, Vt, Cb, Op, Ls);
    hipLaunchKernelGGL(combine_kernel, dim3(2048), dim3(256), 0, stream, Op, Ls, Cb);
  } else {
    hipLaunchKernelGGL(attn_kernel<0>, dim3(1024), dim3(256), 0, stream,
                       Qp, Kp, Vt, Cb, Op, Ls);
  }
  hipLaunchKernelGGL(oproj_kernel, dim3(256), dim3(256), 0, stream, Cb, Wob, bo, out);
}

// Round 6
// 150.468 us; speedup vs baseline: 1.5002x; 1.0813x over previous
//
#include <hip/hip_runtime.h>
#include <hip/hip_bf16.h>

// MultiHeadAttention: B=4, S=2048, D=512, H=16, dh=32 (gfx950)
// Pipeline: wcvt(Wo->bf16) -> proj(QKV per-head, hi/lo split) -> flash attn -> out proj.
// R6: split-K=2 kept (grid 2048) but LDS halved to 8704B/block (single P buffer,
//     qi sequential) -- evidence R3/R4/R5: co-resident LDS ~64KB/CU, so 17408B
//     capped us at 3 blocks/CU. Partials now stored NORMALIZED in bf16 (+f32
//     denom): ctx-scale O(1), bf16-safe, halves partial traffic; combine is a
//     cheap weighted average.

typedef __attribute__((ext_vector_type(8))) short bf16x8;   // 8 bf16 in 4 VGPRs
typedef __attribute__((ext_vector_type(4))) float f32x4;

#define MFMA16(a, b, c) __builtin_amdgcn_mfma_f32_16x16x32_bf16(a, b, c, 0, 0, 0)

static __device__ __forceinline__ unsigned short f2bf(float f) {
  __bf16 h = (__bf16)f;                      // RNE cvt
  union { __bf16 h; unsigned short u; } c; c.h = h; return c.u;
}
static __device__ __forceinline__ float bf2f(unsigned short u) {
  union { unsigned u; float f; } c; c.u = ((unsigned)u) << 16; return c.f;
}

// load 8 consecutive floats, split each into bf16 hi + bf16 residual(lo)
static __device__ __forceinline__ void load8_split(const float* p, bf16x8& hi, bf16x8& lo) {
  float4 a = *(const float4*)p;
  float4 b = *(const float4*)(p + 4);
  float v[8] = {a.x, a.y, a.z, a.w, b.x, b.y, b.z, b.w};
  #pragma unroll
  for (int j = 0; j < 8; ++j) {
    unsigned short h = f2bf(v[j]);
    hi[j] = (short)h;
    lo[j] = (short)f2bf(v[j] - bf2f(h));
  }
}

// ---------------- kernel 1: Wo (512x512 f32) -> bf16 ----------------
__global__ __launch_bounds__(256) void wcvt_kernel(const float* __restrict__ Wo,
                                                   ushort* __restrict__ Wob) {
  int i = (blockIdx.x * 256 + threadIdx.x) * 4;   // grid 256 -> covers 512*512
  float4 v = *(const float4*)&Wo[i];
  ushort4 o;
  o.x = f2bf(v.x); o.y = f2bf(v.y); o.z = f2bf(v.z); o.w = f2bf(v.w);
  *(ushort4*)&Wob[i] = o;
}

// ---------------- kernel 2: per-head projections ----------------
// Qp[bh][s][e] (scaled by log2e/sqrt(32)), Kp[bh][s][e], Vt[bh][e][s]  (bf16)
__global__ __launch_bounds__(256) void proj_kernel(
    const float* __restrict__ key, const float* __restrict__ query,
    const float* __restrict__ value,
    const float* __restrict__ Wq, const float* __restrict__ Wk,
    const float* __restrict__ Wv,
    ushort* __restrict__ Qp, ushort* __restrict__ Kp, ushort* __restrict__ Vt) {
  const int tid = threadIdx.x;
  const int l = tid & 63, wid = tid >> 6;
  const int lr = l & 15, lc = l >> 4;
  const int task = blockIdx.x * 4 + wid;     // 8192 tasks: (b, s-tile16, h)
  const int h = task & 15;
  const int st = (task >> 4) & 127;
  const int b = task >> 11;
  const int bh = b * 16 + h;
  const size_t xoff = ((size_t)b * 2048 + st * 16 + lr) * 512 + h * 32 + lc * 8;
  const float ALPHA = 0.2550354039f;         // log2(e)/sqrt(32)

  #pragma unroll
  for (int t = 0; t < 3; ++t) {
    const float* x = (t == 0) ? query : (t == 1) ? key : value;
    const float* W = (t == 0) ? Wq : (t == 1) ? Wk : Wv;
    bf16x8 xh, xl;
    load8_split(x + xoff, xh, xl);
    #pragma unroll
    for (int eh = 0; eh < 2; ++eh) {
      bf16x8 wh, wl;
      load8_split(W + (size_t)(eh * 16 + lr) * 32 + lc * 8, wh, wl);
      f32x4 acc = {0.f, 0.f, 0.f, 0.f};
      acc = MFMA16(xh, wh, acc);   // hi*hi + hi*lo + lo*hi: ~fp32-accurate projection
      acc = MFMA16(xh, wl, acc);
      acc = MFMA16(xl, wh, acc);
      if (t == 0) {
        #pragma unroll
        for (int r = 0; r < 4; ++r)
          Qp[((size_t)bh * 2048 + st * 16 + lc * 4 + r) * 32 + eh * 16 + lr] =
              f2bf(acc[r] * ALPHA);
      } else if (t == 1) {
        #pragma unroll
        for (int r = 0; r < 4; ++r)
          Kp[((size_t)bh * 2048 + st * 16 + lc * 4 + r) * 32 + eh * 16 + lr] = f2bf(acc[r]);
      } else {                      // V stored transposed: Vt[bh][e][s]
        ushort4 pk;
        pk.x = f2bf(acc[0]); pk.y = f2bf(acc[1]);
        pk.z = f2bf(acc[2]); pk.w = f2bf(acc[3]);
        *(ushort4*)&Vt[((size_t)bh * 32 + eh * 16 + lr) * 2048 + st * 16 + lc * 4] = pk;
      }
    }
  }
}

// ---------------- kernel 3: attention (optionally split-K) ----------------
// SPLIT=1: grid 2048, blockIdx>>10 = k-half (1024 keys each); normalized bf16
//          partials -> Opb, denominators -> Ls.
// SPLIT=0: grid 1024, full 2048 keys, normalized bf16 Cb directly.
// 4 waves * 32 q-rows. Swapped QK: sc = mfma(K,Q) -> D[m=k][n=q]; lane (lr,lc)
// holds k=lc*4+r for q=lr. No max-subtraction (logits in log2 units, |s|<~3).
template <int SPLIT>
__global__ __launch_bounds__(256) void attn_kernel(
    const ushort* __restrict__ Qp, const ushort* __restrict__ Kp,
    const ushort* __restrict__ Vt, ushort* __restrict__ Cb,
    ushort* __restrict__ Opb, float* __restrict__ Ls) {
  // Single per-wave P tile [q=16][k=64], stride 68 ushorts (34 dwords/row ->
  // bank shift 2/row; b64 writes 1 touch/bank, b64-pair reads 2-touch minimum;
  // measured 0 conflicts R1/R3/R5). 8704 B/block -> ~7 blocks per 64KB-CU.
  __shared__ ushort plds[4][16][68];
  const int tid = threadIdx.x;
  const int l = tid & 63, w = tid >> 6;
  const int lr = l & 15, lc = l >> 4;
  const int qpart = SPLIT ? (blockIdx.x & 1023) : blockIdx.x;
  const int kh = SPLIT ? (int)(blockIdx.x >> 10) : 0;
  const int bh = qpart >> 4;
  const int qblk = qpart & 15;
  const int b = bh >> 4, h = bh & 15;
  const int q0 = qblk * 128 + w * 32;

  const ushort* Qb = Qp + (size_t)bh * 2048 * 32;
  const ushort* Kb = Kp + (size_t)bh * 2048 * 32;
  const ushort* Vb = Vt + (size_t)bh * 32 * 2048;

  bf16x8 qf[2];
  qf[0] = *(const bf16x8*)&Qb[(size_t)(q0 + lr) * 32 + lc * 8];
  qf[1] = *(const bf16x8*)&Qb[(size_t)(q0 + 16 + lr) * 32 + lc * 8];

  f32x4 octx[2][2] = {};
  float lsum[2] = {0.f, 0.f};          // lane-local partial denom for q = q0+qi*16+lr
  const f32x4 zero = {0.f, 0.f, 0.f, 0.f};

  const int t0 = SPLIT ? kh * 16 : 0;
  const int t1 = SPLIT ? kh * 16 + 16 : 32;
  for (int kt = t0; kt < t1; ++kt) {
    const int k0 = kt * 64;
    bf16x8 kf[4];
    #pragma unroll
    for (int kg = 0; kg < 4; ++kg)
      kf[kg] = *(const bf16x8*)&Kb[(size_t)(k0 + kg * 16 + lr) * 32 + lc * 8];
    bf16x8 vf[2][2];
    #pragma unroll
    for (int kc = 0; kc < 2; ++kc)
      #pragma unroll
      for (int eh = 0; eh < 2; ++eh)
        vf[kc][eh] = *(const bf16x8*)&Vb[(size_t)(eh * 16 + lr) * 2048 + k0 + kc * 32 + lc * 8];

    // qi sequential over the shared P buffer; in-wave DS ordering guarantees
    // qi0's reads complete before qi1's writes (same-wave DS ops are ordered),
    // and the write->read RAW gets a compiler-counted lgkmcnt. The resulting
    // stall is hidden by ~7 co-resident blocks/CU (the point of this round).
    #pragma unroll
    for (int qi = 0; qi < 2; ++qi) {
      f32x4 sc[4];
      #pragma unroll
      for (int kg = 0; kg < 4; ++kg)
        sc[kg] = MFMA16(kf[kg], qf[qi], zero);   // D[m=k][n=q]
      #pragma unroll
      for (int kg = 0; kg < 4; ++kg) {
        float p0 = __builtin_amdgcn_exp2f(sc[kg][0]);
        float p1 = __builtin_amdgcn_exp2f(sc[kg][1]);
        float p2 = __builtin_amdgcn_exp2f(sc[kg][2]);
        float p3 = __builtin_amdgcn_exp2f(sc[kg][3]);
        lsum[qi] += (p0 + p1) + (p2 + p3);
        ushort4 pk;
        pk.x = f2bf(p0); pk.y = f2bf(p1); pk.z = f2bf(p2); pk.w = f2bf(p3);
        // row q=lr, cols k = kg*16 + lc*4 .. +3 (one 8B write, 8B-aligned)
        *(ushort4*)&plds[w][lr][kg * 16 + lc * 4] = pk;
      }
      #pragma unroll
      for (int kc = 0; kc < 2; ++kc) {
        union { ushort4 q[2]; bf16x8 v; } u;
        u.q[0] = *(const ushort4*)&plds[w][lr][kc * 32 + lc * 8];
        u.q[1] = *(const ushort4*)&plds[w][lr][kc * 32 + lc * 8 + 4];
        #pragma unroll
        for (int eh = 0; eh < 2; ++eh)
          octx[qi][eh] = MFMA16(u.v, vf[kc][eh], octx[qi][eh]);
      }
    }
  }

  // normalize by this block's partial denominator; store bf16 (ctx-scale O(1)).
  #pragma unroll
  for (int qi = 0; qi < 2; ++qi) {
    float s = lsum[qi];
    s += __shfl_xor(s, 16);
    s += __shfl_xor(s, 32);
    float inv[4];
    #pragma unroll
    for (int r = 0; r < 4; ++r)
      inv[r] = 1.0f / __shfl(s, lc * 4 + r);
    if (SPLIT) {
      const size_t rowb = (size_t)bh * 2048 + q0 + qi * 16;
      if (lc == 0) Ls[(size_t)kh * 131072 + rowb + lr] = s;
      #pragma unroll
      for (int eh = 0; eh < 2; ++eh)
        #pragma unroll
        for (int r = 0; r < 4; ++r)
          Opb[((size_t)kh * 131072 + rowb + lc * 4 + r) * 32 + eh * 16 + lr] =
              f2bf(octx[qi][eh][r] * inv[r]);
    } else {
      #pragma unroll
      for (int eh = 0; eh < 2; ++eh)
        #pragma unroll
        for (int r = 0; r < 4; ++r) {
          float v = octx[qi][eh][r] * inv[r];
          Cb[((size_t)b * 2048 + q0 + qi * 16 + lc * 4 + r) * 512 + h * 32 + eh * 16 + lr] =
              f2bf(v);
        }
    }
  }
}

// ---------------- kernel 3b: combine normalized split-K partials -> Cb ----------------
// o = w0*o0 + w1*o1 with w_i = l_i/(l0+l1). grid 2048x256: t -> row=t>>2, e0=(t&3)*8.
__global__ __launch_bounds__(256) void combine_kernel(
    const ushort* __restrict__ Opb, const float* __restrict__ Ls,
    ushort* __restrict__ Cb) {
  const int t = blockIdx.x * 256 + threadIdx.x;
  const int row = t >> 2;           // bh*2048 + q
  const int e0 = (t & 3) * 8;
  const int bh = row >> 11, q = row & 2047;
  const int b = bh >> 4, h = bh & 15;
  const size_t HALF = 131072;

  float l0 = Ls[row], l1 = Ls[HALF + row];
  float w0 = l0 / (l0 + l1), w1 = 1.0f - w0;
  bf16x8 a = *(const bf16x8*)&Opb[(size_t)row * 32 + e0];
  bf16x8 c = *(const bf16x8*)&Opb[(HALF + row) * 32 + e0];
  ushort4 o[2];
  #pragma unroll
  for (int j = 0; j < 8; ++j) {
    float v = w0 * bf2f((unsigned short)a[j]) + w1 * bf2f((unsigned short)c[j]);
    ((ushort*)o)[j] = f2bf(v);
  }
  ushort* dst = &Cb[((size_t)b * 2048 + q) * 512 + h * 32 + e0];
  *(ushort4*)dst = o[0];
  *(ushort4*)(dst + 4) = o[1];
}

// ---------------- kernel 4: out = ctx @ Wo^T + bo ----------------
// grid 256: bid>>1 = 64-row q-tile, bid&1 = 256-col n-half; each wave 64x64.
__global__ __launch_bounds__(256) void oproj_kernel(
    const ushort* __restrict__ Cb, const ushort* __restrict__ Wob,
    const float* __restrict__ bo, float* __restrict__ out) {
  const int tid = threadIdx.x;
  const int l = tid & 63, w = tid >> 6;
  const int lr = l & 15, lc = l >> 4;
  const int qt = blockIdx.x >> 1;
  const int nt = blockIdx.x & 1;
  const int r0 = qt * 64;
  const int n0 = nt * 256 + w * 64;

  f32x4 acc[4][4] = {};
  for (int kk = 0; kk < 16; ++kk) {
    const int k0 = kk * 32;
    bf16x8 af[4], bf[4];
    #pragma unroll
    for (int i = 0; i < 4; ++i)
      af[i] = *(const bf16x8*)&Cb[(size_t)(r0 + i * 16 + lr) * 512 + k0 + lc * 8];
    #pragma unroll
    for (int j = 0; j < 4; ++j)
      bf[j] = *(const bf16x8*)&Wob[(size_t)(n0 + j * 16 + lr) * 512 + k0 + lc * 8];
    #pragma unroll
    for (int i = 0; i < 4; ++i)
      #pragma unroll
      for (int j = 0; j < 4; ++j)
        acc[i][j] = MFMA16(af[i], bf[j], acc[i][j]);
  }
  #pragma unroll
  for (int j = 0; j < 4; ++j) {
    float bias = bo[n0 + j * 16 + lr];
    #pragma unroll
    for (int i = 0; i < 4; ++i)
      #pragma unroll
      for (int r = 0; r < 4; ++r)
        out[(size_t)(r0 + i * 16 + lc * 4 + r) * 512 + n0 + j * 16 + lr] =
            acc[i][j][r] + bias;
  }
}

extern "C" void kernel_launch(void* const* d_in, const int* in_sizes, int n_in,
                              void* d_out, int out_size, void* d_ws, size_t ws_size,
                              hipStream_t stream) {
  (void)in_sizes; (void)n_in; (void)out_size;
  const float* key   = (const float*)d_in[0];
  const float* query = (const float*)d_in[1];
  const float* value = (const float*)d_in[2];
  const float* Wq    = (const float*)d_in[3];
  const float* Wk    = (const float*)d_in[4];
  const float* Wv    = (const float*)d_in[5];
  const float* Wo    = (const float*)d_in[6];
  const float* bo    = (const float*)d_in[7];
  float* out = (float*)d_out;

  // workspace (ushorts): Qp, Kp, Vt, Cb (4.19M each), Wob (262144),
  // Opb (2*131072*32 = 8.39M ushorts), then Ls (2*131072 f32).
  const size_t NT = (size_t)4 * 16 * 2048 * 32;   // 4,194,304
  ushort* ws  = (ushort*)d_ws;
  ushort* Qp  = ws;
  ushort* Kp  = Qp + NT;
  ushort* Vt  = Kp + NT;
  ushort* Cb  = Vt + NT;
  ushort* Wob = Cb + NT;
  ushort* Opb = Wob + 262144;
  float*  Ls  = (float*)(Opb + (size_t)2 * 131072 * 32);
  const size_t need = ((size_t)4 * NT + 262144 + (size_t)2 * 131072 * 32) * 2 +
                      (size_t)2 * 131072 * 4;     // ~51.4 MB
  const bool split = ws_size >= need;

  hipLaunchKernelGGL(wcvt_kernel, dim3(256), dim3(256), 0, stream, Wo, Wob);
  hipLaunchKernelGGL(proj_kernel, dim3(2048), dim3(256), 0, stream,
                     key, query, value, Wq, Wk, Wv, Qp, Kp, Vt);
  if (split) {
    hipLaunchKernelGGL(attn_kernel<1>, dim3(2048), dim3(256), 0, stream,
                       Qp, Kp, Vt, Cb, Opb, Ls);
    hipLaunchKernelGGL(combine_kernel, dim3(2048), dim3(256), 0, stream, Opb, Ls, Cb);
  } else {
    hipLaunchKernelGGL(attn_kernel<0>, dim3(1024), dim3(256), 0, stream,
                       Qp, Kp, Vt, Cb, Opb, Ls);
  }
  hipLaunchKernelGGL(oproj_kernel, dim3(256), dim3(256), 0, stream, Cb, Wob, bo, out);
}